// Round 13
// baseline (319.756 us; speedup 1.0000x reference)
//
#include <hip/hip_runtime.h>
#include <hip/hip_bf16.h>

// Problem constants
constexpr int B = 4, L = 2048, E = 300, D = 128, NH = 4, HD = 128, NL = 3, D2 = 512;
constexpr float EPS = 1e-5f;
constexpr float SCALE = 0.08838834764831843f; // 1/sqrt(128)
constexpr int NCH = 128;             // relay-attention node chunks (16 rows each)

typedef unsigned int uint_t;
typedef unsigned short u16;
typedef short bf16x8 __attribute__((ext_vector_type(8)));
typedef float f32x4 __attribute__((ext_vector_type(4)));

__device__ __forceinline__ u16 f2bf(float f) {
  union { float f; uint_t i; } x; x.f = f;
  uint_t r = x.i + 0x7fffu + ((x.i >> 16) & 1u);
  return (u16)(r >> 16);
}
__device__ __forceinline__ uint_t packbf(float a, float b) {
  return (uint_t)f2bf(a) | ((uint_t)f2bf(b) << 16);
}
__device__ __forceinline__ float2 bf2x2(uint_t u) {
  union { uint_t i; float f; } a, b;
  a.i = (u & 0xffffu) << 16; b.i = u & 0xffff0000u;
  return make_float2(a.f, b.f);
}
struct f8 { float v[8]; };
__device__ __forceinline__ f8 unpack8(uint4 u) {
  f8 r;
  float2 a = bf2x2(u.x); r.v[0] = a.x; r.v[1] = a.y;
  float2 b = bf2x2(u.y); r.v[2] = b.x; r.v[3] = b.y;
  float2 c = bf2x2(u.z); r.v[4] = c.x; r.v[5] = c.y;
  float2 d = bf2x2(u.w); r.v[6] = d.x; r.v[7] = d.y;
  return r;
}

struct WCArgs { const float* s[4]; u16* d[4]; };

// ================= qkv GEMM + riders.
// Grid 1-D: first NPROJ blocks are riders (6 per batch element). Then 1024
// GEMM blocks (64-row A tiles): block computes ALL tensors sharing its A tile
// (group 0: q,k,v from nxb; group 1: ak,av from xb), staging A once and
// cycling W tiles through the second LDS region. Rider scratch is UNION'd
// into the GEMM LDS buffer -> 52.2 KB static -> 3 blocks/CU.
struct GDesc { const u16* A; const u16* W; const float* bias; u16* outb; };
struct GArgs { GDesc d[5]; };
struct PArgs {
  int mode;
  const float* rel_in;                  // relay entering prev layer (mode1) / this layer (mode0)
  const float* pm; const float* ps; const float* pw;   // prev-layer partials
  const float* uprev; const float* cvprev;             // prev-layer u/cvec
  const float* svw; const float* svb;                  // prev-layer sv
  const float* sow; const float* sob;                  // prev-layer so
  float* rel_out;                       // relay entering this layer (mode1)
  const float* rkw; const float* rkb;   // this-layer projection weights (fp32)
  const float* rvw; const float* rvb;
  const float* sqw; const float* sqb;
  const float* skw; const float* skb;
  float* relay_k; float* relay_v;       // [B,D2]
  float* u; float* cvec;                // [B,NH,D], [B,NH]
};
constexpr int NPROJ = 24;               // B * 6 rider blocks

__global__ __launch_bounds__(256) void gemm_qkv(GArgs ga, PArgs pa, int N) {
  __shared__ __align__(16) unsigned char smem[(64 + 128) * 136 * sizeof(u16)];
  int bid = blockIdx.x;
  int t = threadIdx.x;
  if (bid < NPROJ) {
    // ---------- rider: b = bid/6, job j = bid%6 (scratch carved from smem)
    float* rel = (float*)smem;                         // 128 f  (512 B)
    float (*sql2)[HD] = (float(*)[HD])(smem + 512);    // 2x128 f (1024 B)
    float* credp = (float*)(smem + 1536);              // 4 f (16 B)
    float (*wsum2)[D] = (float(*)[D])(smem + 1552);    // 4x128 f (2048 B)
    float* satts = (float*)(smem + 3600);              // 512 f (2048 B)
    float* ecs2 = (float*)(smem + 5648);               // 512 f (2048 B)
    int b = bid / 6, j = bid % 6;
    int wv = t >> 6, lane = t & 63;
    if (pa.mode) {
      // ---- combine prev layer: softmax over NCH=128 chunk partials + relay row
      if (t < D) rel[t] = pa.rel_in[(size_t)b * D + t];
      __syncthreads();
      float2 uu = ((const float2*)(pa.uprev + ((size_t)b * NH + wv) * D))[lane];
      float2 rr = ((const float2*)rel)[lane];
      float pdot = uu.x * rr.x + uu.y * rr.y;
#pragma unroll
      for (int o = 1; o < 64; o <<= 1) pdot += __shfl_xor(pdot, o, 64);
      float s0 = pdot + pa.cvprev[b * NH + wv];
      int bn = b * NH + wv;
      float pmv0 = pa.pm[bn * NCH + lane];
      float pmv1 = pa.pm[bn * NCH + 64 + lane];
      float m = fmaxf(fmaxf(pmv0, pmv1), s0);
#pragma unroll
      for (int o = 1; o < 64; o <<= 1) m = fmaxf(m, __shfl_xor(m, o, 64));
      float ec0 = expf(pmv0 - m), ec1 = expf(pmv1 - m);
      ecs2[wv * NCH + lane] = ec0;
      ecs2[wv * NCH + 64 + lane] = ec1;
      float sc = pa.ps[bn * NCH + lane] * ec0 + pa.ps[bn * NCH + 64 + lane] * ec1;
#pragma unroll
      for (int o = 1; o < 64; o <<= 1) sc += __shfl_xor(sc, o, 64);
      float e0 = expf(s0 - m);
      float invS = 1.0f / (e0 + sc);
      float2 a;
      a.x = e0 * rel[lane * 2]; a.y = e0 * rel[lane * 2 + 1];
      const float* pwb = pa.pw + (size_t)bn * NCH * D;
#pragma unroll 8
      for (int c = 0; c < NCH; c++) {
        float2 pw2 = ((const float2*)(pwb + (size_t)c * D))[lane];
        float e = ecs2[wv * NCH + c];
        a.x += e * pw2.x; a.y += e * pw2.y;
      }
      wsum2[wv][lane * 2] = a.x * invS;
      wsum2[wv][lane * 2 + 1] = a.y * invS;
      __syncthreads();
      // satt = svb + svw . wsum  (512 outputs, 2 passes)
#pragma unroll
      for (int pp = 0; pp < 2; pp++) {
        int nh = pp * 256 + t, n = nh >> 7;
        float acc = pa.svb[nh];
        const float4* wp = (const float4*)(pa.svw + (size_t)nh * D);
        const float4* wl = (const float4*)wsum2[n];
#pragma unroll 8
        for (int dd = 0; dd < D / 4; dd++) {
          float4 x = wl[dd], y = wp[dd];
          acc += x.x * y.x + x.y * y.y + x.z * y.z + x.w * y.w;
        }
        satts[nh] = acc;
      }
      __syncthreads();
      // new relay = leaky(sob + sow . satts), 2-way K-split (rred in ecs2[0:256])
      {
        int part = t >> 7, col = t & 127;
        float acc = 0.f;
        const float4* wp = (const float4*)(pa.sow + (size_t)col * D2 + part * 256);
        const float4* a4 = (const float4*)(satts + part * 256);
#pragma unroll 8
        for (int jj = 0; jj < 64; jj++) {
          float4 x = a4[jj], y = wp[jj];
          acc += x.x * y.x + x.y * y.y + x.z * y.z + x.w * y.w;
        }
        __syncthreads();               // done reading ecs2 as ec
        ecs2[part * 128 + col] = acc;  // rred
      }
      __syncthreads();
      if (t < D) {
        float av = pa.sob[t] + ecs2[t] + ecs2[128 + t];
        av = (av > 0.f) ? av : 0.01f * av;
        rel[t] = av;
        pa.rel_out[(size_t)b * D + t] = av;   // all 6 riders write identical values
      }
      __syncthreads();
    } else {
      if (t < D) rel[t] = pa.rel_in[(size_t)b * D + t];
      __syncthreads();
    }
    // ---- projections from rel (1/6 share per rider)
    const float4* r4 = (const float4*)rel;
    if (j < 4) {
      // relay_k / relay_v: 256 outputs per block (2 blocks per tensor)
      int which = j >> 1;                 // 0 = rk, 1 = rv
      int n = (j & 1) * 256 + t;          // output index 0..511
      const float* W = which ? pa.rvw : pa.rkw;
      float acc = (which ? pa.rvb : pa.rkb)[n];
      const float4* w4 = (const float4*)(W + (size_t)n * D);
#pragma unroll 8
      for (int i = 0; i < D / 4; i++) {
        float4 w = w4[i], r = r4[i];
        acc += w.x * r.x + w.y * r.y + w.z * r.z + w.w * r.w;
      }
      (which ? pa.relay_v : pa.relay_k)[(size_t)b * D2 + n] = acc;
    } else {
      // sq -> sql; u = (sql . skw) * SCALE; cvec = (sql . skb) * SCALE
      // 2 heads per block: head n = (j-4)*2 + (t>=128)
      int hh = t >> 7, th = t & 127;
      int n = (j - 4) * 2 + hh;
      int nh = n * HD + th;
      float acc = pa.sqb[nh];
      const float4* w4 = (const float4*)(pa.sqw + (size_t)nh * D);
#pragma unroll 8
      for (int i = 0; i < D / 4; i++) {
        float4 w = w4[i], r = r4[i];
        acc += w.x * r.x + w.y * r.y + w.z * r.z + w.w * r.w;
      }
      sql2[hh][th] = acc;
      __syncthreads();
      float cp = acc * pa.skb[nh];
#pragma unroll
      for (int o = 1; o < 64; o <<= 1) cp += __shfl_xor(cp, o, 64);
      if ((t & 63) == 0) credp[t >> 6] = cp;
      float a0 = 0.f, a1 = 0.f, a2 = 0.f, a3 = 0.f;
      const float* wp = pa.skw + (size_t)(n * HD) * D + th;
      for (int hx = 0; hx < HD; hx += 4) {
        a0 += sql2[hh][hx] * wp[(size_t)hx * D];
        a1 += sql2[hh][hx + 1] * wp[(size_t)(hx + 1) * D];
        a2 += sql2[hh][hx + 2] * wp[(size_t)(hx + 2) * D];
        a3 += sql2[hh][hx + 3] * wp[(size_t)(hx + 3) * D];
      }
      pa.u[((size_t)b * NH + n) * D + th] = (a0 + a1 + a2 + a3) * SCALE;
      __syncthreads();
      if (th == 0) pa.cvec[b * NH + n] = (credp[2 * hh] + credp[2 * hh + 1]) * SCALE;
    }
    return;
  }
  // ---------- main GEMM path: 64-row A tiles, shared-A multi-tensor block
  u16 (*As)[136] = (u16(*)[136])smem;                       // 64 x 136
  u16 (*Ws)[136] = (u16(*)[136])(smem + 64 * 136 * sizeof(u16));  // 128 x 136
  int g = bid - NPROJ;                 // 0..1023
  int grp = g >> 9;                    // 0: q,k,v (A=nxb); 1: ak,av (A=xb)
  int bm = (g & 511) >> 2, bn = g & 3; // bm 0..127
  const int di0 = grp ? 3 : 0;
  const int ntens = grp ? 2 : 3;
  const int rowA = bm * 64, rowW = bn * 128;

  const int wid = t >> 6;
  const int wm = (wid & 1) * 32, wn = (wid >> 1) * 64;
  const int lr = t & 15, quad = (t >> 4) & 3;
  const int ra = t >> 2, ca = (t & 3) * 32;
  const int rw = t >> 1, cw = (t & 1) * 64;

  // stage A once (64 rows x 128 cols)
  {
    const u16* Arow = ga.d[di0].A + (size_t)(rowA + ra) * 128 + ca;
    uint4 av_[4];
#pragma unroll
    for (int i = 0; i < 4; i++) av_[i] = *(const uint4*)(Arow + i * 8);
#pragma unroll
    for (int i = 0; i < 4; i++) *(uint4*)&As[ra][ca + i * 8] = av_[i];
  }
  for (int ti = 0; ti < ntens; ti++) {
    GDesc d = ga.d[di0 + ti];
    // stage W tile (128 rows x 128 cols) for this tensor
    {
      const u16* Wrow = d.W + (size_t)(rowW + rw) * 128 + cw;
      uint4 wv_[8];
#pragma unroll
      for (int i = 0; i < 8; i++) wv_[i] = *(const uint4*)(Wrow + i * 8);
#pragma unroll
      for (int i = 0; i < 8; i++) *(uint4*)&Ws[rw][cw + i * 8] = wv_[i];
    }
    __syncthreads();                   // As (first iter) + Ws visible
    f32x4 acc[2][4];
#pragma unroll
    for (int i = 0; i < 2; i++)
#pragma unroll
      for (int j = 0; j < 4; j++)
        acc[i][j] = (f32x4){0.f, 0.f, 0.f, 0.f};
#pragma unroll
    for (int ks = 0; ks < 4; ks++) {
      bf16x8 af[2], bfr[4];
#pragma unroll
      for (int mt = 0; mt < 2; mt++)
        af[mt] = *(const bf16x8*)&As[wm + mt * 16 + lr][ks * 32 + quad * 8];
#pragma unroll
      for (int nt = 0; nt < 4; nt++)
        bfr[nt] = *(const bf16x8*)&Ws[wn + nt * 16 + lr][ks * 32 + quad * 8];
#pragma unroll
      for (int mt = 0; mt < 2; mt++)
#pragma unroll
        for (int nt = 0; nt < 4; nt++)
          acc[mt][nt] = __builtin_amdgcn_mfma_f32_16x16x32_bf16(af[mt], bfr[nt], acc[mt][nt], 0, 0, 0);
    }
    __syncthreads();                   // done reading Ws
    // epilogue: bf16 round into Ws rows 0..63, then coalesced uint4 stores
#pragma unroll
    for (int nt = 0; nt < 4; nt++) {
      int colL = wn + nt * 16 + lr;
      float bv = d.bias[rowW + colL];
#pragma unroll
      for (int mt = 0; mt < 2; mt++) {
#pragma unroll
        for (int rr = 0; rr < 4; rr++) {
          int rowL = wm + mt * 16 + quad * 4 + rr;
          Ws[rowL][colL] = f2bf(acc[mt][nt][rr] + bv);
        }
      }
    }
    __syncthreads();
#pragma unroll
    for (int rep = 0; rep < 4; rep++) {
      int lin = rep * 256 + t;
      int rowL = lin >> 4, colL = (lin & 15) * 8;
      uint4 v = *(const uint4*)&Ws[rowL][colL];
      *(uint4*)&d.outb[(size_t)(rowA + rowL) * N + rowW + colL] = v;
    }
    __syncthreads();                   // Ws free for next tensor
  }
}

// ================= embedding projection (gathered A, K=300, 64x128 tile) +
// fused layer-0 LN (-> nxb) + relay mean (atomics) + nodes/xb writes.
// Blocks >= 128 are wconv riders (fp32 -> bf16 weight conversion, 4 tensors).
__global__ __launch_bounds__(256) void gemm_embed_ln(
    WCArgs wa,
    const float* __restrict__ emb, const float* __restrict__ W,
    const float* __restrict__ bias, const int* __restrict__ gather,
    const float* __restrict__ lng, const float* __restrict__ lnb,
    float* __restrict__ nodes, u16* __restrict__ xb, u16* __restrict__ nxb,
    float* __restrict__ relay) {
  int bid = blockIdx.x;
  int t = threadIdx.x;
  if (bid >= 128) {
    int cb = bid - 128;                // 0..767
    int ti = cb / 192, xi = cb - ti * 192;
    const float* s = wa.s[ti]; u16* dd = wa.d[ti];
    int i = (xi * 256 + t) * 4;
    float4 f = *(const float4*)(s + i);
    *(uint2*)(dd + i) = make_uint2(packbf(f.x, f.y), packbf(f.z, f.w));
    return;
  }
  __shared__ u16 As[64][72];
  __shared__ u16 Ws[128][72];
  __shared__ float C[64][132];
  __shared__ float gb[2][D];
  __shared__ float lmu[64], lrs[64];
  int bm = bid;                      // 128 blocks
  const int rowA0 = bm * 64;

  f32x4 acc[2][4];
#pragma unroll
  for (int i = 0; i < 2; i++)
#pragma unroll
    for (int j = 0; j < 4; j++)
      acc[i][j] = (f32x4){0.f, 0.f, 0.f, 0.f};

  const int wid = t >> 6;
  const int wm = (wid & 1) * 32, wn = (wid >> 1) * 64;
  const int lr = t & 15, quad = (t >> 4) & 3;
  const int ra = t >> 2, ca = (t & 3) * 16;
  const int rw = t >> 1, cw = (t & 1) * 32;

  if (t < D) { gb[0][t] = lng[t]; gb[1][t] = lnb[t]; }

  const float* Arow = emb + (size_t)gather[rowA0 + ra] * E;
  const float* Wrow = W + (size_t)rw * E;

  for (int kt = 0; kt < E; kt += 64) {
    __syncthreads();
    bool full = (kt + 64 <= E);
#pragma unroll
    for (int ch = 0; ch < 4; ch++) {
      int c = kt + ca + ch * 4;
      float4 fa;
      if (full) fa = *(const float4*)(Arow + c);
      else {
        fa.x = (c + 0 < E) ? Arow[c + 0] : 0.f;
        fa.y = (c + 1 < E) ? Arow[c + 1] : 0.f;
        fa.z = (c + 2 < E) ? Arow[c + 2] : 0.f;
        fa.w = (c + 3 < E) ? Arow[c + 3] : 0.f;
      }
      *(uint2*)&As[ra][ca + ch * 4] = make_uint2(packbf(fa.x, fa.y), packbf(fa.z, fa.w));
    }
#pragma unroll
    for (int ch = 0; ch < 8; ch++) {
      int c = kt + cw + ch * 4;
      float4 fw;
      if (full) fw = *(const float4*)(Wrow + c);
      else {
        fw.x = (c + 0 < E) ? Wrow[c + 0] : 0.f;
        fw.y = (c + 1 < E) ? Wrow[c + 1] : 0.f;
        fw.z = (c + 2 < E) ? Wrow[c + 2] : 0.f;
        fw.w = (c + 3 < E) ? Wrow[c + 3] : 0.f;
      }
      *(uint2*)&Ws[rw][cw + ch * 4] = make_uint2(packbf(fw.x, fw.y), packbf(fw.z, fw.w));
    }
    __syncthreads();
#pragma unroll
    for (int ks = 0; ks < 2; ks++) {
      bf16x8 af[2], bfr[4];
#pragma unroll
      for (int mt = 0; mt < 2; mt++)
        af[mt] = *(const bf16x8*)&As[wm + mt * 16 + lr][ks * 32 + quad * 8];
#pragma unroll
      for (int nt = 0; nt < 4; nt++)
        bfr[nt] = *(const bf16x8*)&Ws[wn + nt * 16 + lr][ks * 32 + quad * 8];
#pragma unroll
      for (int mt = 0; mt < 2; mt++)
#pragma unroll
        for (int nt = 0; nt < 4; nt++)
          acc[mt][nt] = __builtin_amdgcn_mfma_f32_16x16x32_bf16(af[mt], bfr[nt], acc[mt][nt], 0, 0, 0);
    }
  }
#pragma unroll
  for (int nt = 0; nt < 4; nt++) {
    int col = wn + nt * 16 + lr;
    float bv = bias[col];
#pragma unroll
    for (int mt = 0; mt < 2; mt++) {
#pragma unroll
      for (int rr = 0; rr < 4; rr++) {
        int row = wm + mt * 16 + quad * 4 + rr;
        C[row][col] = acc[mt][nt][rr] + bv;
      }
    }
  }
  __syncthreads();
  if (t < 64) {
    float s = 0.f, s2 = 0.f;
#pragma unroll 16
    for (int j = 0; j < D; j++) { float v = C[t][j]; s += v; s2 += v * v; }
    float mu = s * (1.0f / D);
    float var = s2 * (1.0f / D) - mu * mu;
    lmu[t] = mu; lrs[t] = rsqrtf(var + EPS);
  }
  __syncthreads();
#pragma unroll
  for (int rep = 0; rep < 8; rep++) {
    int lin = rep * 1024 + t * 4;
    int row = lin >> 7, col = lin & 127;
    float4 v = *(const float4*)&C[row][col];
    size_t g = (size_t)(rowA0 + row) * D + col;
    *(float4*)&nodes[g] = v;
    *(uint2*)&xb[g] = make_uint2(packbf(v.x, v.y), packbf(v.z, v.w));
    float mu = lmu[row], rs = lrs[row];
    float o0 = (v.x - mu) * rs * gb[0][col] + gb[1][col];
    float o1 = (v.y - mu) * rs * gb[0][col + 1] + gb[1][col + 1];
    float o2 = (v.z - mu) * rs * gb[0][col + 2] + gb[1][col + 2];
    float o3 = (v.w - mu) * rs * gb[0][col + 3] + gb[1][col + 3];
    *(uint2*)&nxb[g] = make_uint2(packbf(o0, o1), packbf(o2, o3));
  }
  if (t < D) {
    int b = rowA0 >> 11;
    float s = 0.f;
#pragma unroll 16
    for (int r2 = 0; r2 < 64; r2++) s += C[r2][t];
    atomicAdd(&relay[b * D + t], s * (1.0f / L));
  }
}

// ================= FUSED: ring attention (16 rows into LDS) + ro GEMM (K=512,
// staged Ws) + residual + mask + next-layer LN + relay-attention partials.
// grid 512 blocks x 512 threads (Round-11 verified form).
__global__ __launch_bounds__(512) void attn_ro_ln(
    const u16* __restrict__ q, const u16* __restrict__ k, const u16* __restrict__ v,
    const u16* __restrict__ akr, const u16* __restrict__ avr,
    const float* __restrict__ rkvec, const float* __restrict__ rvvec,
    const u16* __restrict__ W,      // ro_w bf16 [128, 512]
    const float* __restrict__ bias, // ro_b [128]
    const int* __restrict__ mask,
    const float* __restrict__ lng, const float* __restrict__ lnb,
    const float* __restrict__ uvec, const float* __restrict__ cvec,
    float* __restrict__ nodes, u16* __restrict__ nxb,
    float* __restrict__ pm, float* __restrict__ ps, float* __restrict__ pw,
    int do_ln) {
  __shared__ u16 att[16][520];       // attention output tile (K-dim 512 + pad)
  __shared__ u16 Ws[128][136];
  __shared__ float C[16][132];
  __shared__ float gb[2][D];
  __shared__ float lmu[16], lrs[16];
  __shared__ float usv[NH][D];
  __shared__ float cv2[NH];
  __shared__ float scs[NH][16];
  __shared__ float esr[NH][16];
  int t = threadIdx.x;
  int bm = blockIdx.x;               // 512 blocks, 16 rows each
  const int rowA0 = bm * 16;
  const int b4 = rowA0 >> 11;
  const int chunk = (rowA0 >> 4) & (NCH - 1);
  const int wid = t >> 6, lane = t & 63;

  if (do_ln && t < D) { gb[0][t] = lng[t]; gb[1][t] = lnb[t]; }
  usv[t >> 7][t & 127] = uvec[(size_t)b4 * NH * D + t];
  if (t < NH) cv2[t] = cvec[b4 * NH + t];

  // ---- Phase A: windowed attention for 16 rows (8 waves x 2 rows)
  {
    size_t rb = (size_t)b4 * D2 + lane * 8;
    float4 rk0 = *(const float4*)(rkvec + rb), rk1 = *(const float4*)(rkvec + rb + 4);
    float4 rv0 = *(const float4*)(rvvec + rb), rv1 = *(const float4*)(rvvec + rb + 4);
    f8 krel, vrel;
    krel.v[0] = rk0.x; krel.v[1] = rk0.y; krel.v[2] = rk0.z; krel.v[3] = rk0.w;
    krel.v[4] = rk1.x; krel.v[5] = rk1.y; krel.v[6] = rk1.z; krel.v[7] = rk1.w;
    vrel.v[0] = rv0.x; vrel.v[1] = rv0.y; vrel.v[2] = rv0.z; vrel.v[3] = rv0.w;
    vrel.v[4] = rv1.x; vrel.v[5] = rv1.y; vrel.v[6] = rv1.z; vrel.v[7] = rv1.w;
#pragma unroll
    for (int i = 0; i < 2; i++) {
      int rr_ = wid * 2 + i;
      int gr = rowA0 + rr_;
      int l = gr & (L - 1);
      size_t rowoff = (size_t)gr * D2 + lane * 8;
      uint4 qd = *(const uint4*)(q + rowoff);
      uint4 kd[4], vd[4];
#pragma unroll
      for (int u2 = 0; u2 < 3; u2++) {
        int ll = l + u2 - 1;
        bool ok = (ll >= 0 && ll < L);
        size_t off = rowoff + (size_t)(u2 - 1) * (size_t)D2;
        if (ok) { kd[u2] = *(const uint4*)(k + off); vd[u2] = *(const uint4*)(v + off); }
        else { kd[u2] = make_uint4(0, 0, 0, 0); vd[u2] = make_uint4(0, 0, 0, 0); }
      }
      kd[3] = *(const uint4*)(akr + rowoff);
      vd[3] = *(const uint4*)(avr + rowoff);
      f8 qf = unpack8(qd);
      f8 kf[5], vf[5];
#pragma unroll
      for (int u2 = 0; u2 < 4; u2++) { kf[u2] = unpack8(kd[u2]); vf[u2] = unpack8(vd[u2]); }
      kf[4] = krel; vf[4] = vrel;
      float s[5];
#pragma unroll
      for (int u2 = 0; u2 < 5; u2++) {
        float p = 0.f;
#pragma unroll
        for (int j = 0; j < 8; j++) p += qf.v[j] * kf[u2].v[j];
#pragma unroll
        for (int o = 1; o < 16; o <<= 1) p += __shfl_xor(p, o, 64);
        s[u2] = p * SCALE;
      }
      float m = s[0];
#pragma unroll
      for (int u2 = 1; u2 < 5; u2++) m = fmaxf(m, s[u2]);
      float e[5], sum = 0.f;
#pragma unroll
      for (int u2 = 0; u2 < 5; u2++) { e[u2] = expf(s[u2] - m); sum += e[u2]; }
      float inv = 1.0f / sum;
      float o8[8];
#pragma unroll
      for (int j = 0; j < 8; j++) {
        float a = 0.f;
#pragma unroll
        for (int u2 = 0; u2 < 5; u2++) a += e[u2] * vf[u2].v[j];
        o8[j] = a * inv;
      }
      uint4 od;
      od.x = packbf(o8[0], o8[1]); od.y = packbf(o8[2], o8[3]);
      od.z = packbf(o8[4], o8[5]); od.w = packbf(o8[6], o8[7]);
      *(uint4*)&att[rr_][lane * 8] = od;
    }
  }
  __syncthreads();

  // ---- Phase B: ro GEMM 16x128, K=512 (A = att tile in LDS, staged Ws)
  // wave wid covers output cols [wid*16, wid*16+16), all 16 rows.
  f32x4 acc;
  acc = (f32x4){0.f, 0.f, 0.f, 0.f};
  const int wn = wid * 16;
  const int lr = t & 15, quad = (t >> 4) & 3;
  const int rw = t >> 2, cw = (t & 3) * 32;
  const u16* Wrow = W + (size_t)rw * 512;
  for (int kt = 0; kt < 512; kt += 128) {
    uint4 w0 = *(const uint4*)(Wrow + kt + cw);
    uint4 w1 = *(const uint4*)(Wrow + kt + cw + 8);
    uint4 w2 = *(const uint4*)(Wrow + kt + cw + 16);
    uint4 w3 = *(const uint4*)(Wrow + kt + cw + 24);
    __syncthreads();
    *(uint4*)&Ws[rw][cw] = w0; *(uint4*)&Ws[rw][cw + 8] = w1;
    *(uint4*)&Ws[rw][cw + 16] = w2; *(uint4*)&Ws[rw][cw + 24] = w3;
    __syncthreads();
#pragma unroll
    for (int ks = 0; ks < 4; ks++) {
      bf16x8 af = *(const bf16x8*)&att[lr][kt + ks * 32 + quad * 8];
      bf16x8 bfr = *(const bf16x8*)&Ws[wn + lr][ks * 32 + quad * 8];
      acc = __builtin_amdgcn_mfma_f32_16x16x32_bf16(af, bfr, acc, 0, 0, 0);
    }
  }
  __syncthreads();
  // ---- Phase C: bias + leaky + residual + mask -> C
  {
    int col = wn + lr;
    float bv = bias[col];
#pragma unroll
    for (int rr = 0; rr < 4; rr++) {
      int row = quad * 4 + rr;
      float vv = acc[rr] + bv;
      vv = (vv > 0.f) ? vv : 0.01f * vv;
      vv += nodes[(size_t)(rowA0 + row) * D + col];
      if (mask[rowA0 + row] == 0) vv = 0.f;
      C[row][col] = vv;
    }
  }
  __syncthreads();
  if (t < 16) {
    float s = 0.f, s2 = 0.f;
#pragma unroll 16
    for (int j = 0; j < D; j++) { float vv = C[t][j]; s += vv; s2 += vv * vv; }
    float mu = s * (1.0f / D);
    float var = s2 * (1.0f / D) - mu * mu;
    lmu[t] = mu; lrs[t] = rsqrtf(var + EPS);
  }
  __syncthreads();
  {
    int lin = t * 4;
    int row = lin >> 7, col = lin & 127;
    float4 vv = *(const float4*)&C[row][col];
    size_t g = (size_t)(rowA0 + row) * D + col;
    *(float4*)&nodes[g] = vv;
    if (do_ln) {
      float mu = lmu[row], rs = lrs[row];
      float o0 = (vv.x - mu) * rs * gb[0][col] + gb[1][col];
      float o1 = (vv.y - mu) * rs * gb[0][col + 1] + gb[1][col + 1];
      float o2 = (vv.z - mu) * rs * gb[0][col + 2] + gb[1][col + 2];
      float o3 = (vv.w - mu) * rs * gb[0][col + 3] + gb[1][col + 3];
      *(uint2*)&nxb[g] = make_uint2(packbf(o0, o1), packbf(o2, o3));
    }
  }
  // ---- Phase F: relay-attention partials (waves 0..3, wave = head)
  if (wid < 4) {
    int n = wid;
    int bn = b4 * NH + n;
    const float2* un = (const float2*)usv[n];
    float2 uv2 = un[lane];
    for (int r2 = 0; r2 < 16; r2++) {
      float2 cc = ((const float2*)&C[r2][0])[lane];
      float p = uv2.x * cc.x + uv2.y * cc.y;
#pragma unroll
      for (int o = 1; o < 64; o <<= 1) p += __shfl_xor(p, o, 64);
      if (lane == 0) {
        float s = p + cv2[n];
        if (mask[rowA0 + r2] == 0) s = -1e30f;
        scs[n][r2] = s;
      }
    }
    float m = -1e30f;
    for (int r2 = 0; r2 < 16; r2++) m = fmaxf(m, scs[n][r2]);
    if (lane < 16) esr[n][lane] = expf(scs[n][lane] - m);
    float sum = 0.f;
    for (int r2 = 0; r2 < 16; r2++) sum += esr[n][r2];
    if (lane == 0) { pm[bn * NCH + chunk] = m; ps[bn * NCH + chunk] = sum; }
    float a0 = 0.f, a1 = 0.f;
    for (int r2 = 0; r2 < 16; r2++) {
      float e = esr[n][r2];
      float2 cc = ((const float2*)&C[r2][0])[lane];
      a0 += e * cc.x; a1 += e * cc.y;
    }
    float* pwp = pw + ((size_t)bn * NCH + chunk) * D + 2 * lane;
    pwp[0] = a0; pwp[1] = a1;
  }
}

// ================= final relay combine (last layer only): grid B x 512 thr.
__global__ __launch_bounds__(512) void relay_combine(
    const float* __restrict__ pm, const float* __restrict__ ps,
    const float* __restrict__ pw,
    const float* __restrict__ relay_entry,
    const float* __restrict__ uvec_in, const float* __restrict__ cvec_in,
    const float* __restrict__ svw, const float* __restrict__ svb,
    const float* __restrict__ sow, const float* __restrict__ sob,
    float* __restrict__ relay_out) {
  __shared__ float rel0[D];
  __shared__ float wpart[8];
  __shared__ float ecs[NH][NCH];
  __shared__ float wsum[NH][D];
  __shared__ float satts[D2];
  __shared__ float rred[4][D];
  int b = blockIdx.x, t = threadIdx.x;
  int n = t >> 7, h = t & 127;
  int w = t >> 6, lane = t & 63;
  if (t < D) rel0[t] = relay_entry[(size_t)b * D + t];
  __syncthreads();
  float p = uvec_in[((size_t)b * NH + n) * D + h] * rel0[h];
#pragma unroll
  for (int o = 1; o < 64; o <<= 1) p += __shfl_xor(p, o, 64);
  if (lane == 0) wpart[w] = p;
  __syncthreads();
  float s0 = wpart[2 * n] + wpart[2 * n + 1] + cvec_in[b * NH + n];
  // per-head max over NCH=128 chunk maxima + s0 (each lane handles 2 chunks;
  // both waves of a head compute identical values: c = h & 63)
  int c = h & 63;
  float pmv0 = pm[(b * NH + n) * NCH + c];
  float pmv1 = pm[(b * NH + n) * NCH + 64 + c];
  float m = fmaxf(fmaxf(pmv0, pmv1), s0);
#pragma unroll
  for (int o = 1; o < 64; o <<= 1) m = fmaxf(m, __shfl_xor(m, o, 64));
  float ec0 = expf(pmv0 - m), ec1 = expf(pmv1 - m);
  if (h < 64) { ecs[n][h] = ec0; ecs[n][64 + h] = ec1; }
  float sc = ps[(b * NH + n) * NCH + c] * ec0 + ps[(b * NH + n) * NCH + 64 + c] * ec1;
#pragma unroll
  for (int o = 1; o < 64; o <<= 1) sc += __shfl_xor(sc, o, 64);
  float e0 = expf(s0 - m);
  float invS = 1.0f / (e0 + sc);
  __syncthreads();
  float acc = e0 * rel0[h];
  const float* pwp = pw + ((size_t)(b * NH + n) * NCH) * D + h;
#pragma unroll 8
  for (int cc = 0; cc < NCH; cc++) acc += ecs[n][cc] * pwp[(size_t)cc * D];
  wsum[n][h] = acc * invS;
  __syncthreads();
  {
    float a = svb[t];
    const float4* wp = (const float4*)(svw + (size_t)t * D);
    const float4* wl = (const float4*)wsum[n];
#pragma unroll 8
    for (int dd = 0; dd < D / 4; dd++) {
      float4 x = wl[dd], y = wp[dd];
      a += x.x * y.x + x.y * y.y + x.z * y.z + x.w * y.w;
    }
    satts[t] = a;
  }
  __syncthreads();
  {
    int part = t >> 7, col = t & 127;
    float a = 0.f;
    const float4* wp = (const float4*)(sow + (size_t)col * D2 + part * 128);
    const float4* a4 = (const float4*)(satts + part * 128);
#pragma unroll 8
    for (int jj = 0; jj < 32; jj++) {
      float4 x = a4[jj], y = wp[jj];
      a += x.x * y.x + x.y * y.y + x.z * y.z + x.w * y.w;
    }
    rred[part][col] = a;
  }
  __syncthreads();
  if (t < D) {
    float a = sob[t] + rred[0][t] + rred[1][t] + rred[2][t] + rred[3][t];
    a = (a > 0.f) ? a : 0.01f * a;
    relay_out[(size_t)b * D + t] = a;
  }
}

extern "C" void kernel_launch(void* const* d_in, const int* in_sizes, int n_in,
                              void* d_out, int out_size, void* d_ws, size_t ws_size,
                              hipStream_t stream) {
  const int* tokens = (const int*)d_in[0];
  const int* mask = (const int*)d_in[1];
  const float* emb = (const float*)d_in[2];
  const float* proj_w = (const float*)d_in[3];
  const float* proj_b = (const float*)d_in[4];
  const float* ng = (const float*)d_in[5];
  const float* nb = (const float*)d_in[6];
  const float* rq_w = (const float*)d_in[7], * rq_b = (const float*)d_in[8];
  const float* rk_w = (const float*)d_in[9], * rk_b = (const float*)d_in[10];
  const float* rv_w = (const float*)d_in[11], * rv_b = (const float*)d_in[12];
  const float* ro_w = (const float*)d_in[13], * ro_b = (const float*)d_in[14];
  const float* sq_w = (const float*)d_in[15], * sq_b = (const float*)d_in[16];
  const float* sk_w = (const float*)d_in[17], * sk_b = (const float*)d_in[18];
  const float* sv_w = (const float*)d_in[19], * sv_b = (const float*)d_in[20];
  const float* so_w = (const float*)d_in[21], * so_b = (const float*)d_in[22];

  const size_t BLD = (size_t)B * L * D;        // 1,048,576
  const size_t BLD4 = (size_t)B * L * D2;      // 4,194,304
  const size_t WTEN = (size_t)NL * D * D2;     // 196,608 per tensor

  float* fp = (float*)d_ws;
  float* nodes = fp;                    fp += BLD;
  float* rbuf0 = fp;                    fp += B * D;
  float* rbuf1 = fp;                    fp += B * D;
  float* relay_k = fp;                  fp += B * D2;
  float* relay_v = fp;                  fp += B * D2;
  float* uv0 = fp;                      fp += B * NH * D;
  float* uv1 = fp;                      fp += B * NH * D;
  float* cv0 = fp;                      fp += B * NH;
  float* cv1 = fp;                      fp += B * NH;
  float* pm = fp;                       fp += B * NH * NCH;
  float* ps = fp;                       fp += B * NH * NCH;
  float* pw = fp;                       fp += (size_t)B * NH * NCH * D;
  u16* up = (u16*)fp;
  u16* xb = up;                         up += BLD;
  u16* nxb = up;                        up += BLD;
  u16* qb = up;                         up += BLD4;
  u16* kb = up;                         up += BLD4;
  u16* vb = up;                         up += BLD4;
  u16* akb = up;                        up += BLD4;
  u16* avb = up;                        up += BLD4;
  u16* wb = up;                         // 4 * WTEN
  u16* wrq = wb, * wrk = wb + WTEN, * wrv = wb + 2 * WTEN, * wro = wb + 3 * WTEN;

  float* uv[2] = {uv0, uv1};
  float* cv[2] = {cv0, cv1};

  hipMemsetAsync(rbuf0, 0, B * D * sizeof(float), stream);

  // embedding projection + layer-0 LN + relay mean; blocks >=128 do weight conv
  {
    WCArgs wa;
    wa.s[0] = rq_w; wa.s[1] = rk_w; wa.s[2] = rv_w; wa.s[3] = ro_w;
    wa.d[0] = wrq; wa.d[1] = wrk; wa.d[2] = wrv; wa.d[3] = wro;
    gemm_embed_ln<<<128 + 768, 256, 0, stream>>>(wa, emb, proj_w, proj_b, tokens,
                                                 ng, nb, nodes, xb, nxb, rbuf0);
  }

  // relay entering layer i lives in: i=0 -> rbuf0; i=1 -> rbuf1; i=2 -> rbuf0
  float* rel_in_l[3] = {rbuf0, rbuf0, rbuf1};  // rider input (prev relay)
  float* rel_out_l[3] = {nullptr, rbuf1, rbuf0};

  for (int i = 0; i < NL; i++) {
    const size_t wo = (size_t)i * D * D2;
    const float* rqbi = rq_b + (size_t)i * D2;
    const float* rkbi = rk_b + (size_t)i * D2;
    const float* rvbi = rv_b + (size_t)i * D2;
    const float* robi = ro_b + (size_t)i * D;
    const int e = i & 1, ep = (i > 0) ? ((i - 1) & 1) : 0;
    const int last = (i == NL - 1);

    // q,k,v (from nxb) + ak,av (from xb) GEMMs (64-row shared-A blocks);
    // 24 riders combine prev layer's relay partials (i>0) + projections.
    {
      GArgs ga = {};
      ga.d[0] = {nxb, wrq + wo, rqbi, qb};
      ga.d[1] = {nxb, wrk + wo, rkbi, kb};
      ga.d[2] = {nxb, wrv + wo, rvbi, vb};
      ga.d[3] = {xb,  wrk + wo, rkbi, akb};
      ga.d[4] = {xb,  wrv + wo, rvbi, avb};
      PArgs pa;
      pa.mode = (i == 0) ? 0 : 1;
      pa.rel_in = rel_in_l[i];
      pa.pm = pm; pa.ps = ps; pa.pw = pw;
      pa.uprev = uv[ep]; pa.cvprev = cv[ep];
      const size_t wprev = (size_t)(i > 0 ? i - 1 : 0) * D * D2;
      pa.svw = sv_w + wprev; pa.svb = sv_b + (size_t)(i > 0 ? i - 1 : 0) * D2;
      pa.sow = so_w + wprev; pa.sob = so_b + (size_t)(i > 0 ? i - 1 : 0) * D;
      pa.rel_out = rel_out_l[i];
      pa.rkw = rk_w + wo; pa.rkb = rkbi;
      pa.rvw = rv_w + wo; pa.rvb = rvbi;
      pa.sqw = sq_w + wo; pa.sqb = sq_b + (size_t)i * D2;
      pa.skw = sk_w + wo; pa.skb = sk_b + (size_t)i * D2;
      pa.relay_k = relay_k; pa.relay_v = relay_v; pa.u = uv[e]; pa.cvec = cv[e];
      gemm_qkv<<<1024 + NPROJ, 256, 0, stream>>>(ga, pa, D2);
    }
    // fused ring attention + ro GEMM + residual + mask + LN + relay partials
    attn_ro_ln<<<512, 512, 0, stream>>>(
        qb, kb, vb, akb, avb, relay_k, relay_v,
        wro + wo, robi, mask,
        last ? nullptr : ng + (i + 1) * D, last ? nullptr : nb + (i + 1) * D,
        uv[e], cv[e], nodes, nxb, pm, ps, pw, last ? 0 : 1);
  }
  // final combine: relay entering L2 = rbuf0; layer-2 partials/u/cv -> d_out
  const size_t w2 = (size_t)(NL - 1) * D * D2;
  relay_combine<<<B, 512, 0, stream>>>(pm, ps, pw, rbuf0,
                                       uv[(NL - 1) & 1], cv[(NL - 1) & 1],
                                       sv_w + w2, sv_b + (size_t)(NL - 1) * D2,
                                       so_w + w2, so_b + (size_t)(NL - 1) * D,
                                       (float*)d_out);
}

// Round 14
// 309.270 us; speedup vs baseline: 1.0339x; 1.0339x over previous
//
#include <hip/hip_runtime.h>
#include <hip/hip_bf16.h>

// Problem constants
constexpr int B = 4, L = 2048, E = 300, D = 128, NH = 4, HD = 128, NL = 3, D2 = 512;
constexpr float EPS = 1e-5f;
constexpr float SCALE = 0.08838834764831843f; // 1/sqrt(128)
constexpr int NCH = 128;             // relay-attention node chunks (16 rows each)

typedef unsigned int uint_t;
typedef unsigned short u16;
typedef short bf16x8 __attribute__((ext_vector_type(8)));
typedef float f32x4 __attribute__((ext_vector_type(4)));

__device__ __forceinline__ u16 f2bf(float f) {
  union { float f; uint_t i; } x; x.f = f;
  uint_t r = x.i + 0x7fffu + ((x.i >> 16) & 1u);
  return (u16)(r >> 16);
}
__device__ __forceinline__ uint_t packbf(float a, float b) {
  return (uint_t)f2bf(a) | ((uint_t)f2bf(b) << 16);
}
__device__ __forceinline__ float2 bf2x2(uint_t u) {
  union { uint_t i; float f; } a, b;
  a.i = (u & 0xffffu) << 16; b.i = u & 0xffff0000u;
  return make_float2(a.f, b.f);
}
struct f8 { float v[8]; };
__device__ __forceinline__ f8 unpack8(uint4 u) {
  f8 r;
  float2 a = bf2x2(u.x); r.v[0] = a.x; r.v[1] = a.y;
  float2 b = bf2x2(u.y); r.v[2] = b.x; r.v[3] = b.y;
  float2 c = bf2x2(u.z); r.v[4] = c.x; r.v[5] = c.y;
  float2 d = bf2x2(u.w); r.v[6] = d.x; r.v[7] = d.y;
  return r;
}

struct WCArgs { const float* s[4]; u16* d[4]; };

// ================= qkv GEMM + riders.
// Grid 1-D: first NPROJ blocks are riders (6 per batch element). Then 512 GEMM
// blocks: block computes ALL tensors sharing its A tile (group 0: q,k,v from
// nxb; group 1: ak,av from xb), staging A once and cycling W tiles through the
// second LDS buffer (Round-8 verified form).
struct GDesc { const u16* A; const u16* W; const float* bias; u16* outb; };
struct GArgs { GDesc d[5]; };
struct PArgs {
  int mode;
  const float* rel_in;                  // relay entering prev layer (mode1) / this layer (mode0)
  const float* pm; const float* ps; const float* pw;   // prev-layer partials
  const float* uprev; const float* cvprev;             // prev-layer u/cvec
  const float* svw; const float* svb;                  // prev-layer sv
  const float* sow; const float* sob;                  // prev-layer so
  float* rel_out;                       // relay entering this layer (mode1)
  const float* rkw; const float* rkb;   // this-layer projection weights (fp32)
  const float* rvw; const float* rvb;
  const float* sqw; const float* sqb;
  const float* skw; const float* skb;
  float* relay_k; float* relay_v;       // [B,D2]
  float* u; float* cvec;                // [B,NH,D], [B,NH]
};
constexpr int NPROJ = 24;               // B * 6 rider blocks

__global__ __launch_bounds__(256) void gemm_qkv(GArgs ga, PArgs pa, int N) {
  int bid = blockIdx.x;
  int t = threadIdx.x;
  if (bid < NPROJ) {
    // ---------- rider: b = bid/6, job j = bid%6
    __shared__ float rel[D];
    __shared__ float sql2[2][HD];
    __shared__ float credp[4];
    __shared__ float wsum2[NH][D];
    __shared__ float satts[D2];
    __shared__ float ecs2[NH * NCH];   // ec per head (combine); tail reused as rred[2][128]
    int b = bid / 6, j = bid % 6;
    int wv = t >> 6, lane = t & 63;
    if (pa.mode) {
      // ---- combine prev layer: softmax over NCH=128 chunk partials + relay row
      if (t < D) rel[t] = pa.rel_in[(size_t)b * D + t];
      __syncthreads();
      float2 uu = ((const float2*)(pa.uprev + ((size_t)b * NH + wv) * D))[lane];
      float2 rr = ((const float2*)rel)[lane];
      float pdot = uu.x * rr.x + uu.y * rr.y;
#pragma unroll
      for (int o = 1; o < 64; o <<= 1) pdot += __shfl_xor(pdot, o, 64);
      float s0 = pdot + pa.cvprev[b * NH + wv];
      int bn = b * NH + wv;
      float pmv0 = pa.pm[bn * NCH + lane];
      float pmv1 = pa.pm[bn * NCH + 64 + lane];
      float m = fmaxf(fmaxf(pmv0, pmv1), s0);
#pragma unroll
      for (int o = 1; o < 64; o <<= 1) m = fmaxf(m, __shfl_xor(m, o, 64));
      float ec0 = expf(pmv0 - m), ec1 = expf(pmv1 - m);
      ecs2[wv * NCH + lane] = ec0;
      ecs2[wv * NCH + 64 + lane] = ec1;
      float sc = pa.ps[bn * NCH + lane] * ec0 + pa.ps[bn * NCH + 64 + lane] * ec1;
#pragma unroll
      for (int o = 1; o < 64; o <<= 1) sc += __shfl_xor(sc, o, 64);
      float e0 = expf(s0 - m);
      float invS = 1.0f / (e0 + sc);
      float2 a;
      a.x = e0 * rel[lane * 2]; a.y = e0 * rel[lane * 2 + 1];
      const float* pwb = pa.pw + (size_t)bn * NCH * D;
#pragma unroll 8
      for (int c = 0; c < NCH; c++) {
        float2 pw2 = ((const float2*)(pwb + (size_t)c * D))[lane];
        float e = ecs2[wv * NCH + c];
        a.x += e * pw2.x; a.y += e * pw2.y;
      }
      wsum2[wv][lane * 2] = a.x * invS;
      wsum2[wv][lane * 2 + 1] = a.y * invS;
      __syncthreads();
      // satt = svb + svw . wsum  (512 outputs, 2 passes)
#pragma unroll
      for (int pp = 0; pp < 2; pp++) {
        int nh = pp * 256 + t, n = nh >> 7;
        float acc = pa.svb[nh];
        const float4* wp = (const float4*)(pa.svw + (size_t)nh * D);
        const float4* wl = (const float4*)wsum2[n];
#pragma unroll 8
        for (int dd = 0; dd < D / 4; dd++) {
          float4 x = wl[dd], y = wp[dd];
          acc += x.x * y.x + x.y * y.y + x.z * y.z + x.w * y.w;
        }
        satts[nh] = acc;
      }
      __syncthreads();
      // new relay = leaky(sob + sow . satts), 2-way K-split (rred in ecs2[0:256])
      {
        int part = t >> 7, col = t & 127;
        float acc = 0.f;
        const float4* wp = (const float4*)(pa.sow + (size_t)col * D2 + part * 256);
        const float4* a4 = (const float4*)(satts + part * 256);
#pragma unroll 8
        for (int jj = 0; jj < 64; jj++) {
          float4 x = a4[jj], y = wp[jj];
          acc += x.x * y.x + x.y * y.y + x.z * y.z + x.w * y.w;
        }
        __syncthreads();               // done reading ecs2 as ec (wsum phase long past)
        ecs2[part * 128 + col] = acc;  // rred
      }
      __syncthreads();
      if (t < D) {
        float av = pa.sob[t] + ecs2[t] + ecs2[128 + t];
        av = (av > 0.f) ? av : 0.01f * av;
        rel[t] = av;
        pa.rel_out[(size_t)b * D + t] = av;   // all 6 riders write identical values
      }
      __syncthreads();
    } else {
      if (t < D) rel[t] = pa.rel_in[(size_t)b * D + t];
      __syncthreads();
    }
    // ---- projections from rel (1/6 share per rider)
    const float4* r4 = (const float4*)rel;
    if (j < 4) {
      // relay_k / relay_v: 256 outputs per block (2 blocks per tensor)
      int which = j >> 1;                 // 0 = rk, 1 = rv
      int n = (j & 1) * 256 + t;          // output index 0..511
      const float* W = which ? pa.rvw : pa.rkw;
      float acc = (which ? pa.rvb : pa.rkb)[n];
      const float4* w4 = (const float4*)(W + (size_t)n * D);
#pragma unroll 8
      for (int i = 0; i < D / 4; i++) {
        float4 w = w4[i], r = r4[i];
        acc += w.x * r.x + w.y * r.y + w.z * r.z + w.w * r.w;
      }
      (which ? pa.relay_v : pa.relay_k)[(size_t)b * D2 + n] = acc;
    } else {
      // sq -> sql; u = (sql . skw) * SCALE; cvec = (sql . skb) * SCALE
      // 2 heads per block: head n = (j-4)*2 + (t>=128)
      int hh = t >> 7, th = t & 127;
      int n = (j - 4) * 2 + hh;
      int nh = n * HD + th;
      float acc = pa.sqb[nh];
      const float4* w4 = (const float4*)(pa.sqw + (size_t)nh * D);
#pragma unroll 8
      for (int i = 0; i < D / 4; i++) {
        float4 w = w4[i], r = r4[i];
        acc += w.x * r.x + w.y * r.y + w.z * r.z + w.w * r.w;
      }
      sql2[hh][th] = acc;
      __syncthreads();
      float cp = acc * pa.skb[nh];
#pragma unroll
      for (int o = 1; o < 64; o <<= 1) cp += __shfl_xor(cp, o, 64);
      if ((t & 63) == 0) credp[t >> 6] = cp;
      float a0 = 0.f, a1 = 0.f, a2 = 0.f, a3 = 0.f;
      const float* wp = pa.skw + (size_t)(n * HD) * D + th;
      for (int hx = 0; hx < HD; hx += 4) {
        a0 += sql2[hh][hx] * wp[(size_t)hx * D];
        a1 += sql2[hh][hx + 1] * wp[(size_t)(hx + 1) * D];
        a2 += sql2[hh][hx + 2] * wp[(size_t)(hx + 2) * D];
        a3 += sql2[hh][hx + 3] * wp[(size_t)(hx + 3) * D];
      }
      pa.u[((size_t)b * NH + n) * D + th] = (a0 + a1 + a2 + a3) * SCALE;
      __syncthreads();
      if (th == 0) pa.cvec[b * NH + n] = (credp[2 * hh] + credp[2 * hh + 1]) * SCALE;
    }
    return;
  }
  // ---------- main GEMM path: shared-A multi-tensor block (Round-8 form)
  __shared__ u16 As[128][136];
  __shared__ u16 Ws[128][136];
  int g = bid - NPROJ;                 // 0..511
  int grp = g >> 8;                    // 0: q,k,v (A=nxb); 1: ak,av (A=xb)
  int bm = (g & 255) >> 2, bn = g & 3;
  const int di0 = grp ? 3 : 0;
  const int ntens = grp ? 2 : 3;
  const int rowA = bm * 128, rowW = bn * 128;

  const int r = t >> 1, c0 = (t & 1) * 64;
  const int wid = t >> 6;
  const int wm = (wid & 1) * 64, wn = (wid >> 1) * 64;
  const int lr = t & 15, quad = (t >> 4) & 3;

  // stage A once
  {
    const u16* Arow = ga.d[di0].A + (size_t)(rowA + r) * 128;
    uint4 av_[8];
#pragma unroll
    for (int i = 0; i < 8; i++) av_[i] = *(const uint4*)(Arow + c0 + i * 8);
#pragma unroll
    for (int i = 0; i < 8; i++) *(uint4*)&As[r][c0 + i * 8] = av_[i];
  }
  for (int ti = 0; ti < ntens; ti++) {
    GDesc d = ga.d[di0 + ti];
    // stage W tile for this tensor
    {
      const u16* Wrow = d.W + (size_t)(rowW + r) * 128;
      uint4 wv_[8];
#pragma unroll
      for (int i = 0; i < 8; i++) wv_[i] = *(const uint4*)(Wrow + c0 + i * 8);
#pragma unroll
      for (int i = 0; i < 8; i++) *(uint4*)&Ws[r][c0 + i * 8] = wv_[i];
    }
    __syncthreads();                   // As (first iter) + Ws visible
    f32x4 acc[4][4];
#pragma unroll
    for (int i = 0; i < 4; i++)
#pragma unroll
      for (int j = 0; j < 4; j++)
        acc[i][j] = (f32x4){0.f, 0.f, 0.f, 0.f};
#pragma unroll
    for (int ks = 0; ks < 4; ks++) {
      bf16x8 af[4], bfr[4];
#pragma unroll
      for (int mt = 0; mt < 4; mt++)
        af[mt] = *(const bf16x8*)&As[wm + mt * 16 + lr][ks * 32 + quad * 8];
#pragma unroll
      for (int nt = 0; nt < 4; nt++)
        bfr[nt] = *(const bf16x8*)&Ws[wn + nt * 16 + lr][ks * 32 + quad * 8];
#pragma unroll
      for (int mt = 0; mt < 4; mt++)
#pragma unroll
        for (int nt = 0; nt < 4; nt++)
          acc[mt][nt] = __builtin_amdgcn_mfma_f32_16x16x32_bf16(af[mt], bfr[nt], acc[mt][nt], 0, 0, 0);
    }
    __syncthreads();                   // done reading Ws
    // epilogue: bf16 round into Ws, then coalesced uint4 stores
#pragma unroll
    for (int nt = 0; nt < 4; nt++) {
      int colL = wn + nt * 16 + lr;
      float bv = d.bias[rowW + colL];
#pragma unroll
      for (int mt = 0; mt < 4; mt++) {
#pragma unroll
        for (int rr = 0; rr < 4; rr++) {
          int rowL = wm + mt * 16 + quad * 4 + rr;
          Ws[rowL][colL] = f2bf(acc[mt][nt][rr] + bv);
        }
      }
    }
    __syncthreads();
#pragma unroll
    for (int rep = 0; rep < 8; rep++) {
      int lin = rep * 256 + t;
      int rowL = lin >> 4, colL = (lin & 15) * 8;
      uint4 v = *(const uint4*)&Ws[rowL][colL];
      *(uint4*)&d.outb[(size_t)(rowA + rowL) * N + rowW + colL] = v;
    }
    __syncthreads();                   // Ws free for next tensor
  }
}

// ================= embedding projection (gathered A, K=300, 64x128 tile) +
// fused layer-0 LN (-> nxb) + relay mean (atomics) + nodes/xb writes.
// Blocks >= 128 are wconv riders (fp32 -> bf16 weight conversion, 4 tensors).
__global__ __launch_bounds__(256) void gemm_embed_ln(
    WCArgs wa,
    const float* __restrict__ emb, const float* __restrict__ W,
    const float* __restrict__ bias, const int* __restrict__ gather,
    const float* __restrict__ lng, const float* __restrict__ lnb,
    float* __restrict__ nodes, u16* __restrict__ xb, u16* __restrict__ nxb,
    float* __restrict__ relay) {
  int bid = blockIdx.x;
  int t = threadIdx.x;
  if (bid >= 128) {
    int cb = bid - 128;                // 0..767
    int ti = cb / 192, xi = cb - ti * 192;
    const float* s = wa.s[ti]; u16* dd = wa.d[ti];
    int i = (xi * 256 + t) * 4;
    float4 f = *(const float4*)(s + i);
    *(uint2*)(dd + i) = make_uint2(packbf(f.x, f.y), packbf(f.z, f.w));
    return;
  }
  __shared__ u16 As[64][72];
  __shared__ u16 Ws[128][72];
  __shared__ float C[64][132];
  __shared__ float gb[2][D];
  __shared__ float lmu[64], lrs[64];
  int bm = bid;                      // 128 blocks
  const int rowA0 = bm * 64;

  f32x4 acc[2][4];
#pragma unroll
  for (int i = 0; i < 2; i++)
#pragma unroll
    for (int j = 0; j < 4; j++)
      acc[i][j] = (f32x4){0.f, 0.f, 0.f, 0.f};

  const int wid = t >> 6;
  const int wm = (wid & 1) * 32, wn = (wid >> 1) * 64;
  const int lr = t & 15, quad = (t >> 4) & 3;
  const int ra = t >> 2, ca = (t & 3) * 16;
  const int rw = t >> 1, cw = (t & 1) * 32;

  if (t < D) { gb[0][t] = lng[t]; gb[1][t] = lnb[t]; }

  const float* Arow = emb + (size_t)gather[rowA0 + ra] * E;
  const float* Wrow = W + (size_t)rw * E;

  for (int kt = 0; kt < E; kt += 64) {
    __syncthreads();
    bool full = (kt + 64 <= E);
#pragma unroll
    for (int ch = 0; ch < 4; ch++) {
      int c = kt + ca + ch * 4;
      float4 fa;
      if (full) fa = *(const float4*)(Arow + c);
      else {
        fa.x = (c + 0 < E) ? Arow[c + 0] : 0.f;
        fa.y = (c + 1 < E) ? Arow[c + 1] : 0.f;
        fa.z = (c + 2 < E) ? Arow[c + 2] : 0.f;
        fa.w = (c + 3 < E) ? Arow[c + 3] : 0.f;
      }
      *(uint2*)&As[ra][ca + ch * 4] = make_uint2(packbf(fa.x, fa.y), packbf(fa.z, fa.w));
    }
#pragma unroll
    for (int ch = 0; ch < 8; ch++) {
      int c = kt + cw + ch * 4;
      float4 fw;
      if (full) fw = *(const float4*)(Wrow + c);
      else {
        fw.x = (c + 0 < E) ? Wrow[c + 0] : 0.f;
        fw.y = (c + 1 < E) ? Wrow[c + 1] : 0.f;
        fw.z = (c + 2 < E) ? Wrow[c + 2] : 0.f;
        fw.w = (c + 3 < E) ? Wrow[c + 3] : 0.f;
      }
      *(uint2*)&Ws[rw][cw + ch * 4] = make_uint2(packbf(fw.x, fw.y), packbf(fw.z, fw.w));
    }
    __syncthreads();
#pragma unroll
    for (int ks = 0; ks < 2; ks++) {
      bf16x8 af[2], bfr[4];
#pragma unroll
      for (int mt = 0; mt < 2; mt++)
        af[mt] = *(const bf16x8*)&As[wm + mt * 16 + lr][ks * 32 + quad * 8];
#pragma unroll
      for (int nt = 0; nt < 4; nt++)
        bfr[nt] = *(const bf16x8*)&Ws[wn + nt * 16 + lr][ks * 32 + quad * 8];
#pragma unroll
      for (int mt = 0; mt < 2; mt++)
#pragma unroll
        for (int nt = 0; nt < 4; nt++)
          acc[mt][nt] = __builtin_amdgcn_mfma_f32_16x16x32_bf16(af[mt], bfr[nt], acc[mt][nt], 0, 0, 0);
    }
  }
#pragma unroll
  for (int nt = 0; nt < 4; nt++) {
    int col = wn + nt * 16 + lr;
    float bv = bias[col];
#pragma unroll
    for (int mt = 0; mt < 2; mt++) {
#pragma unroll
      for (int rr = 0; rr < 4; rr++) {
        int row = wm + mt * 16 + quad * 4 + rr;
        C[row][col] = acc[mt][nt][rr] + bv;
      }
    }
  }
  __syncthreads();
  if (t < 64) {
    float s = 0.f, s2 = 0.f;
#pragma unroll 16
    for (int j = 0; j < D; j++) { float v = C[t][j]; s += v; s2 += v * v; }
    float mu = s * (1.0f / D);
    float var = s2 * (1.0f / D) - mu * mu;
    lmu[t] = mu; lrs[t] = rsqrtf(var + EPS);
  }
  __syncthreads();
#pragma unroll
  for (int rep = 0; rep < 8; rep++) {
    int lin = rep * 1024 + t * 4;
    int row = lin >> 7, col = lin & 127;
    float4 v = *(const float4*)&C[row][col];
    size_t g = (size_t)(rowA0 + row) * D + col;
    *(float4*)&nodes[g] = v;
    *(uint2*)&xb[g] = make_uint2(packbf(v.x, v.y), packbf(v.z, v.w));
    float mu = lmu[row], rs = lrs[row];
    float o0 = (v.x - mu) * rs * gb[0][col] + gb[1][col];
    float o1 = (v.y - mu) * rs * gb[0][col + 1] + gb[1][col + 1];
    float o2 = (v.z - mu) * rs * gb[0][col + 2] + gb[1][col + 2];
    float o3 = (v.w - mu) * rs * gb[0][col + 3] + gb[1][col + 3];
    *(uint2*)&nxb[g] = make_uint2(packbf(o0, o1), packbf(o2, o3));
  }
  if (t < D) {
    int b = rowA0 >> 11;
    float s = 0.f;
#pragma unroll 16
    for (int r2 = 0; r2 < 64; r2++) s += C[r2][t];
    atomicAdd(&relay[b * D + t], s * (1.0f / L));
  }
}

// ================= FUSED: ring attention (16 rows into LDS) + ro GEMM (K=512,
// staged Ws) + residual + mask + next-layer LN + relay-attention partials.
// grid 512 blocks x 512 threads, ~64 KB LDS -> 2 blocks co-resident/CU.
__global__ __launch_bounds__(512) void attn_ro_ln(
    const u16* __restrict__ q, const u16* __restrict__ k, const u16* __restrict__ v,
    const u16* __restrict__ akr, const u16* __restrict__ avr,
    const float* __restrict__ rkvec, const float* __restrict__ rvvec,
    const u16* __restrict__ W,      // ro_w bf16 [128, 512]
    const float* __restrict__ bias, // ro_b [128]
    const int* __restrict__ mask,
    const float* __restrict__ lng, const float* __restrict__ lnb,
    const float* __restrict__ uvec, const float* __restrict__ cvec,
    float* __restrict__ nodes, u16* __restrict__ nxb,
    float* __restrict__ pm, float* __restrict__ ps, float* __restrict__ pw,
    int do_ln) {
  __shared__ u16 att[16][520];       // attention output tile (K-dim 512 + pad)
  __shared__ u16 Ws[128][136];
  __shared__ float C[16][132];
  __shared__ float gb[2][D];
  __shared__ float lmu[16], lrs[16];
  __shared__ float usv[NH][D];
  __shared__ float cv2[NH];
  __shared__ float scs[NH][16];
  __shared__ float esr[NH][16];
  int t = threadIdx.x;
  int bm = blockIdx.x;               // 512 blocks, 16 rows each
  const int rowA0 = bm * 16;
  const int b4 = rowA0 >> 11;
  const int chunk = (rowA0 >> 4) & (NCH - 1);
  const int wid = t >> 6, lane = t & 63;

  if (do_ln && t < D) { gb[0][t] = lng[t]; gb[1][t] = lnb[t]; }
  usv[t >> 7][t & 127] = uvec[(size_t)b4 * NH * D + t];
  if (t < NH) cv2[t] = cvec[b4 * NH + t];

  // ---- Phase A: windowed attention for 16 rows (8 waves x 2 rows)
  {
    size_t rb = (size_t)b4 * D2 + lane * 8;
    float4 rk0 = *(const float4*)(rkvec + rb), rk1 = *(const float4*)(rkvec + rb + 4);
    float4 rv0 = *(const float4*)(rvvec + rb), rv1 = *(const float4*)(rvvec + rb + 4);
    f8 krel, vrel;
    krel.v[0] = rk0.x; krel.v[1] = rk0.y; krel.v[2] = rk0.z; krel.v[3] = rk0.w;
    krel.v[4] = rk1.x; krel.v[5] = rk1.y; krel.v[6] = rk1.z; krel.v[7] = rk1.w;
    vrel.v[0] = rv0.x; vrel.v[1] = rv0.y; vrel.v[2] = rv0.z; vrel.v[3] = rv0.w;
    vrel.v[4] = rv1.x; vrel.v[5] = rv1.y; vrel.v[6] = rv1.z; vrel.v[7] = rv1.w;
#pragma unroll
    for (int i = 0; i < 2; i++) {
      int rr_ = wid * 2 + i;
      int gr = rowA0 + rr_;
      int l = gr & (L - 1);
      size_t rowoff = (size_t)gr * D2 + lane * 8;
      uint4 qd = *(const uint4*)(q + rowoff);
      uint4 kd[4], vd[4];
#pragma unroll
      for (int u2 = 0; u2 < 3; u2++) {
        int ll = l + u2 - 1;
        bool ok = (ll >= 0 && ll < L);
        size_t off = rowoff + (size_t)(u2 - 1) * (size_t)D2;
        if (ok) { kd[u2] = *(const uint4*)(k + off); vd[u2] = *(const uint4*)(v + off); }
        else { kd[u2] = make_uint4(0, 0, 0, 0); vd[u2] = make_uint4(0, 0, 0, 0); }
      }
      kd[3] = *(const uint4*)(akr + rowoff);
      vd[3] = *(const uint4*)(avr + rowoff);
      f8 qf = unpack8(qd);
      f8 kf[5], vf[5];
#pragma unroll
      for (int u2 = 0; u2 < 4; u2++) { kf[u2] = unpack8(kd[u2]); vf[u2] = unpack8(vd[u2]); }
      kf[4] = krel; vf[4] = vrel;
      float s[5];
#pragma unroll
      for (int u2 = 0; u2 < 5; u2++) {
        float p = 0.f;
#pragma unroll
        for (int j = 0; j < 8; j++) p += qf.v[j] * kf[u2].v[j];
#pragma unroll
        for (int o = 1; o < 16; o <<= 1) p += __shfl_xor(p, o, 64);
        s[u2] = p * SCALE;
      }
      float m = s[0];
#pragma unroll
      for (int u2 = 1; u2 < 5; u2++) m = fmaxf(m, s[u2]);
      float e[5], sum = 0.f;
#pragma unroll
      for (int u2 = 0; u2 < 5; u2++) { e[u2] = expf(s[u2] - m); sum += e[u2]; }
      float inv = 1.0f / sum;
      float o8[8];
#pragma unroll
      for (int j = 0; j < 8; j++) {
        float a = 0.f;
#pragma unroll
        for (int u2 = 0; u2 < 5; u2++) a += e[u2] * vf[u2].v[j];
        o8[j] = a * inv;
      }
      uint4 od;
      od.x = packbf(o8[0], o8[1]); od.y = packbf(o8[2], o8[3]);
      od.z = packbf(o8[4], o8[5]); od.w = packbf(o8[6], o8[7]);
      *(uint4*)&att[rr_][lane * 8] = od;
    }
  }
  __syncthreads();

  // ---- Phase B: ro GEMM 16x128, K=512 (A = att tile in LDS, staged Ws)
  // wave wid covers output cols [wid*16, wid*16+16), all 16 rows.
  f32x4 acc;
  acc = (f32x4){0.f, 0.f, 0.f, 0.f};
  const int wn = wid * 16;
  const int lr = t & 15, quad = (t >> 4) & 3;
  const int rw = t >> 2, cw = (t & 3) * 32;
  const u16* Wrow = W + (size_t)rw * 512;
  for (int kt = 0; kt < 512; kt += 128) {
    uint4 w0 = *(const uint4*)(Wrow + kt + cw);
    uint4 w1 = *(const uint4*)(Wrow + kt + cw + 8);
    uint4 w2 = *(const uint4*)(Wrow + kt + cw + 16);
    uint4 w3 = *(const uint4*)(Wrow + kt + cw + 24);
    __syncthreads();
    *(uint4*)&Ws[rw][cw] = w0; *(uint4*)&Ws[rw][cw + 8] = w1;
    *(uint4*)&Ws[rw][cw + 16] = w2; *(uint4*)&Ws[rw][cw + 24] = w3;
    __syncthreads();
#pragma unroll
    for (int ks = 0; ks < 4; ks++) {
      bf16x8 af = *(const bf16x8*)&att[lr][kt + ks * 32 + quad * 8];
      bf16x8 bfr = *(const bf16x8*)&Ws[wn + lr][ks * 32 + quad * 8];
      acc = __builtin_amdgcn_mfma_f32_16x16x32_bf16(af, bfr, acc, 0, 0, 0);
    }
  }
  __syncthreads();
  // ---- Phase C: bias + leaky + residual + mask -> C
  {
    int col = wn + lr;
    float bv = bias[col];
#pragma unroll
    for (int rr = 0; rr < 4; rr++) {
      int row = quad * 4 + rr;
      float vv = acc[rr] + bv;
      vv = (vv > 0.f) ? vv : 0.01f * vv;
      vv += nodes[(size_t)(rowA0 + row) * D + col];
      if (mask[rowA0 + row] == 0) vv = 0.f;
      C[row][col] = vv;
    }
  }
  __syncthreads();
  if (t < 16) {
    float s = 0.f, s2 = 0.f;
#pragma unroll 16
    for (int j = 0; j < D; j++) { float vv = C[t][j]; s += vv; s2 += vv * vv; }
    float mu = s * (1.0f / D);
    float var = s2 * (1.0f / D) - mu * mu;
    lmu[t] = mu; lrs[t] = rsqrtf(var + EPS);
  }
  __syncthreads();
  {
    int lin = t * 4;
    int row = lin >> 7, col = lin & 127;
    float4 vv = *(const float4*)&C[row][col];
    size_t g = (size_t)(rowA0 + row) * D + col;
    *(float4*)&nodes[g] = vv;
    if (do_ln) {
      float mu = lmu[row], rs = lrs[row];
      float o0 = (vv.x - mu) * rs * gb[0][col] + gb[1][col];
      float o1 = (vv.y - mu) * rs * gb[0][col + 1] + gb[1][col + 1];
      float o2 = (vv.z - mu) * rs * gb[0][col + 2] + gb[1][col + 2];
      float o3 = (vv.w - mu) * rs * gb[0][col + 3] + gb[1][col + 3];
      *(uint2*)&nxb[g] = make_uint2(packbf(o0, o1), packbf(o2, o3));
    }
  }
  // ---- Phase F: relay-attention partials (waves 0..3, wave = head)
  if (wid < 4) {
    int n = wid;
    int bn = b4 * NH + n;
    const float2* un = (const float2*)usv[n];
    float2 uv2 = un[lane];
    for (int r2 = 0; r2 < 16; r2++) {
      float2 cc = ((const float2*)&C[r2][0])[lane];
      float p = uv2.x * cc.x + uv2.y * cc.y;
#pragma unroll
      for (int o = 1; o < 64; o <<= 1) p += __shfl_xor(p, o, 64);
      if (lane == 0) {
        float s = p + cv2[n];
        if (mask[rowA0 + r2] == 0) s = -1e30f;
        scs[n][r2] = s;
      }
    }
    float m = -1e30f;
    for (int r2 = 0; r2 < 16; r2++) m = fmaxf(m, scs[n][r2]);
    if (lane < 16) esr[n][lane] = expf(scs[n][lane] - m);
    float sum = 0.f;
    for (int r2 = 0; r2 < 16; r2++) sum += esr[n][r2];
    if (lane == 0) { pm[bn * NCH + chunk] = m; ps[bn * NCH + chunk] = sum; }
    float a0 = 0.f, a1 = 0.f;
    for (int r2 = 0; r2 < 16; r2++) {
      float e = esr[n][r2];
      float2 cc = ((const float2*)&C[r2][0])[lane];
      a0 += e * cc.x; a1 += e * cc.y;
    }
    float* pwp = pw + ((size_t)bn * NCH + chunk) * D + 2 * lane;
    pwp[0] = a0; pwp[1] = a1;
  }
}

// ================= final relay combine (last layer only): grid B x 512 thr.
__global__ __launch_bounds__(512) void relay_combine(
    const float* __restrict__ pm, const float* __restrict__ ps,
    const float* __restrict__ pw,
    const float* __restrict__ relay_entry,
    const float* __restrict__ uvec_in, const float* __restrict__ cvec_in,
    const float* __restrict__ svw, const float* __restrict__ svb,
    const float* __restrict__ sow, const float* __restrict__ sob,
    float* __restrict__ relay_out) {
  __shared__ float rel0[D];
  __shared__ float wpart[8];
  __shared__ float ecs[NH][NCH];
  __shared__ float wsum[NH][D];
  __shared__ float satts[D2];
  __shared__ float rred[4][D];
  int b = blockIdx.x, t = threadIdx.x;
  int n = t >> 7, h = t & 127;
  int w = t >> 6, lane = t & 63;
  if (t < D) rel0[t] = relay_entry[(size_t)b * D + t];
  __syncthreads();
  float p = uvec_in[((size_t)b * NH + n) * D + h] * rel0[h];
#pragma unroll
  for (int o = 1; o < 64; o <<= 1) p += __shfl_xor(p, o, 64);
  if (lane == 0) wpart[w] = p;
  __syncthreads();
  float s0 = wpart[2 * n] + wpart[2 * n + 1] + cvec_in[b * NH + n];
  // per-head max over NCH=128 chunk maxima + s0 (each lane handles 2 chunks;
  // both waves of a head compute identical values: c = h & 63)
  int c = h & 63;
  float pmv0 = pm[(b * NH + n) * NCH + c];
  float pmv1 = pm[(b * NH + n) * NCH + 64 + c];
  float m = fmaxf(fmaxf(pmv0, pmv1), s0);
#pragma unroll
  for (int o = 1; o < 64; o <<= 1) m = fmaxf(m, __shfl_xor(m, o, 64));
  float ec0 = expf(pmv0 - m), ec1 = expf(pmv1 - m);
  if (h < 64) { ecs[n][h] = ec0; ecs[n][64 + h] = ec1; }
  float sc = ps[(b * NH + n) * NCH + c] * ec0 + ps[(b * NH + n) * NCH + 64 + c] * ec1;
#pragma unroll
  for (int o = 1; o < 64; o <<= 1) sc += __shfl_xor(sc, o, 64);
  float e0 = expf(s0 - m);
  float invS = 1.0f / (e0 + sc);
  __syncthreads();
  float acc = e0 * rel0[h];
  const float* pwp = pw + ((size_t)(b * NH + n) * NCH) * D + h;
#pragma unroll 8
  for (int cc = 0; cc < NCH; cc++) acc += ecs[n][cc] * pwp[(size_t)cc * D];
  wsum[n][h] = acc * invS;
  __syncthreads();
  {
    float a = svb[t];
    const float4* wp = (const float4*)(svw + (size_t)t * D);
    const float4* wl = (const float4*)wsum[n];
#pragma unroll 8
    for (int dd = 0; dd < D / 4; dd++) {
      float4 x = wl[dd], y = wp[dd];
      a += x.x * y.x + x.y * y.y + x.z * y.z + x.w * y.w;
    }
    satts[t] = a;
  }
  __syncthreads();
  {
    int part = t >> 7, col = t & 127;
    float a = 0.f;
    const float4* wp = (const float4*)(sow + (size_t)col * D2 + part * 128);
    const float4* a4 = (const float4*)(satts + part * 128);
#pragma unroll 8
    for (int jj = 0; jj < 32; jj++) {
      float4 x = a4[jj], y = wp[jj];
      a += x.x * y.x + x.y * y.y + x.z * y.z + x.w * y.w;
    }
    rred[part][col] = a;
  }
  __syncthreads();
  if (t < D) {
    float a = sob[t] + rred[0][t] + rred[1][t] + rred[2][t] + rred[3][t];
    a = (a > 0.f) ? a : 0.01f * a;
    relay_out[(size_t)b * D + t] = a;
  }
}

extern "C" void kernel_launch(void* const* d_in, const int* in_sizes, int n_in,
                              void* d_out, int out_size, void* d_ws, size_t ws_size,
                              hipStream_t stream) {
  const int* tokens = (const int*)d_in[0];
  const int* mask = (const int*)d_in[1];
  const float* emb = (const float*)d_in[2];
  const float* proj_w = (const float*)d_in[3];
  const float* proj_b = (const float*)d_in[4];
  const float* ng = (const float*)d_in[5];
  const float* nb = (const float*)d_in[6];
  const float* rq_w = (const float*)d_in[7], * rq_b = (const float*)d_in[8];
  const float* rk_w = (const float*)d_in[9], * rk_b = (const float*)d_in[10];
  const float* rv_w = (const float*)d_in[11], * rv_b = (const float*)d_in[12];
  const float* ro_w = (const float*)d_in[13], * ro_b = (const float*)d_in[14];
  const float* sq_w = (const float*)d_in[15], * sq_b = (const float*)d_in[16];
  const float* sk_w = (const float*)d_in[17], * sk_b = (const float*)d_in[18];
  const float* sv_w = (const float*)d_in[19], * sv_b = (const float*)d_in[20];
  const float* so_w = (const float*)d_in[21], * so_b = (const float*)d_in[22];

  const size_t BLD = (size_t)B * L * D;        // 1,048,576
  const size_t BLD4 = (size_t)B * L * D2;      // 4,194,304
  const size_t WTEN = (size_t)NL * D * D2;     // 196,608 per tensor

  float* fp = (float*)d_ws;
  float* nodes = fp;                    fp += BLD;
  float* rbuf0 = fp;                    fp += B * D;
  float* rbuf1 = fp;                    fp += B * D;
  float* relay_k = fp;                  fp += B * D2;
  float* relay_v = fp;                  fp += B * D2;
  float* uv0 = fp;                      fp += B * NH * D;
  float* uv1 = fp;                      fp += B * NH * D;
  float* cv0 = fp;                      fp += B * NH;
  float* cv1 = fp;                      fp += B * NH;
  float* pm = fp;                       fp += B * NH * NCH;
  float* ps = fp;                       fp += B * NH * NCH;
  float* pw = fp;                       fp += (size_t)B * NH * NCH * D;
  u16* up = (u16*)fp;
  u16* xb = up;                         up += BLD;
  u16* nxb = up;                        up += BLD;
  u16* qb = up;                         up += BLD4;
  u16* kb = up;                         up += BLD4;
  u16* vb = up;                         up += BLD4;
  u16* akb = up;                        up += BLD4;
  u16* avb = up;                        up += BLD4;
  u16* wb = up;                         // 4 * WTEN
  u16* wrq = wb, * wrk = wb + WTEN, * wrv = wb + 2 * WTEN, * wro = wb + 3 * WTEN;

  float* uv[2] = {uv0, uv1};
  float* cv[2] = {cv0, cv1};

  hipMemsetAsync(rbuf0, 0, B * D * sizeof(float), stream);

  // embedding projection + layer-0 LN + relay mean; blocks >=128 do weight conv
  {
    WCArgs wa;
    wa.s[0] = rq_w; wa.s[1] = rk_w; wa.s[2] = rv_w; wa.s[3] = ro_w;
    wa.d[0] = wrq; wa.d[1] = wrk; wa.d[2] = wrv; wa.d[3] = wro;
    gemm_embed_ln<<<128 + 768, 256, 0, stream>>>(wa, emb, proj_w, proj_b, tokens,
                                                 ng, nb, nodes, xb, nxb, rbuf0);
  }

  // relay entering layer i lives in: i=0 -> rbuf0; i=1 -> rbuf1; i=2 -> rbuf0
  float* rel_in_l[3] = {rbuf0, rbuf0, rbuf1};  // rider input (prev relay)
  float* rel_out_l[3] = {nullptr, rbuf1, rbuf0};

  for (int i = 0; i < NL; i++) {
    const size_t wo = (size_t)i * D * D2;
    const float* rqbi = rq_b + (size_t)i * D2;
    const float* rkbi = rk_b + (size_t)i * D2;
    const float* rvbi = rv_b + (size_t)i * D2;
    const float* robi = ro_b + (size_t)i * D;
    const int e = i & 1, ep = (i > 0) ? ((i - 1) & 1) : 0;
    const int last = (i == NL - 1);

    // q,k,v (from nxb) + ak,av (from xb) GEMMs (shared-A blocks); 24 riders
    // combine prev layer's relay partials (i>0) + this layer's projections.
    {
      GArgs ga = {};
      ga.d[0] = {nxb, wrq + wo, rqbi, qb};
      ga.d[1] = {nxb, wrk + wo, rkbi, kb};
      ga.d[2] = {nxb, wrv + wo, rvbi, vb};
      ga.d[3] = {xb,  wrk + wo, rkbi, akb};
      ga.d[4] = {xb,  wrv + wo, rvbi, avb};
      PArgs pa;
      pa.mode = (i == 0) ? 0 : 1;
      pa.rel_in = rel_in_l[i];
      pa.pm = pm; pa.ps = ps; pa.pw = pw;
      pa.uprev = uv[ep]; pa.cvprev = cv[ep];
      const size_t wprev = (size_t)(i > 0 ? i - 1 : 0) * D * D2;
      pa.svw = sv_w + wprev; pa.svb = sv_b + (size_t)(i > 0 ? i - 1 : 0) * D2;
      pa.sow = so_w + wprev; pa.sob = so_b + (size_t)(i > 0 ? i - 1 : 0) * D;
      pa.rel_out = rel_out_l[i];
      pa.rkw = rk_w + wo; pa.rkb = rkbi;
      pa.rvw = rv_w + wo; pa.rvb = rvbi;
      pa.sqw = sq_w + wo; pa.sqb = sq_b + (size_t)i * D2;
      pa.skw = sk_w + wo; pa.skb = sk_b + (size_t)i * D2;
      pa.relay_k = relay_k; pa.relay_v = relay_v; pa.u = uv[e]; pa.cvec = cv[e];
      gemm_qkv<<<512 + NPROJ, 256, 0, stream>>>(ga, pa, D2);
    }
    // fused ring attention + ro GEMM + residual + mask + LN + relay partials
    attn_ro_ln<<<512, 512, 0, stream>>>(
        qb, kb, vb, akb, avb, relay_k, relay_v,
        wro + wo, robi, mask,
        last ? nullptr : ng + (i + 1) * D, last ? nullptr : nb + (i + 1) * D,
        uv[e], cv[e], nodes, nxb, pm, ps, pw, last ? 0 : 1);
  }
  // final combine: relay entering L2 = rbuf0; layer-2 partials/u/cv -> d_out
  const size_t w2 = (size_t)(NL - 1) * D * D2;
  relay_combine<<<B, 512, 0, stream>>>(pm, ps, pw, rbuf0,
                                       uv[(NL - 1) & 1], cv[(NL - 1) & 1],
                                       sv_w + w2, sv_b + (size_t)(NL - 1) * D2,
                                       so_w + w2, so_b + (size_t)(NL - 1) * D,
                                       (float*)d_out);
}